// Round 1
// baseline (235.350 us; speedup 1.0000x reference)
//
#include <hip/hip_runtime.h>
#include <hip/hip_bf16.h>

#define R_ 512
#define K_ 250
#define E_ 16
#define L_ 2

// fold 1/sqrt(D)=0.5 and log2(e) into q so softmax prob = exp2(dot)
#define SCALE_LOG2E 0.72134752044448170f

__global__ __launch_bounds__(256, 2)
void mlra_kernel(const float* __restrict__ pv,       // [R*K,8]
                 const int*   __restrict__ ele_idx,  // [R*K]
                 const int*   __restrict__ azi_idx,  // [R*K]
                 const float* __restrict__ vp_w,     // [8,8]
                 const float* __restrict__ vp_b,     // [8]
                 const float* __restrict__ ele_emb,  // [37,4]
                 const float* __restrict__ azi_emb,  // [107,4]
                 const float* __restrict__ ipw,      // [2,48,16]
                 const float* __restrict__ ipb,      // [2,48]
                 const float* __restrict__ outw,     // [2,16,16]
                 const float* __restrict__ outb,     // [2,16]
                 const float* __restrict__ lng,      // [16]
                 const float* __restrict__ lnb,      // [16]
                 float* __restrict__ out)            // [R*K,16]
{
    __shared__ float s_k[K_][E_];       // 16000 B
    __shared__ float s_v[K_][E_];       // 16000 B
    __shared__ float s_w[48 * 16];      // current layer in_proj weight
    __shared__ float s_b[48];
    __shared__ float s_ow[16 * 16];
    __shared__ float s_ob[16];
    __shared__ float s_vpw[64];
    __shared__ float s_vpb[8];
    __shared__ float s_ele[37 * 4];
    __shared__ float s_azi[107 * 4];
    __shared__ float s_lng[16], s_lnb[16];

    const int r   = blockIdx.x;
    const int tid = threadIdx.x;

    // ---- stage small constant tables ----
    if (tid < 64)  s_vpw[tid] = vp_w[tid];
    if (tid < 8)   s_vpb[tid] = vp_b[tid];
    for (int i = tid; i < 37 * 4;  i += 256) s_ele[i] = ele_emb[i];
    for (int i = tid; i < 107 * 4; i += 256) s_azi[i] = azi_emb[i];
    if (tid < 16) { s_lng[tid] = lng[tid]; s_lnb[tid] = lnb[tid]; }
    __syncthreads();

    const bool act = tid < K_;
    const int  row = r * K_ + tid;

    // ---- prologue: x = concat(pv @ vp_w^T + vp_b, ele_emb[ei], azi_emb[ai]) ----
    float x[16];
    if (act) {
        const float4 p0 = ((const float4*)(pv + (size_t)row * 8))[0];
        const float4 p1 = ((const float4*)(pv + (size_t)row * 8))[1];
        const float pvv[8] = {p0.x, p0.y, p0.z, p0.w, p1.x, p1.y, p1.z, p1.w};
        #pragma unroll
        for (int o = 0; o < 8; ++o) {
            float a = s_vpb[o];
            #pragma unroll
            for (int i = 0; i < 8; ++i) a = fmaf(pvv[i], s_vpw[o * 8 + i], a);
            x[o] = a;
        }
        const int ei = ele_idx[row];
        const int ai = azi_idx[row];
        #pragma unroll
        for (int d = 0; d < 4; ++d) x[8 + d]  = s_ele[ei * 4 + d];
        #pragma unroll
        for (int d = 0; d < 4; ++d) x[12 + d] = s_azi[ai * 4 + d];
    }

    for (int l = 0; l < L_; ++l) {
        __syncthreads();   // previous-layer LDS consumers done before overwrite
        // stage layer weights
        for (int i = tid; i < 768; i += 256) s_w[i] = ipw[l * 768 + i];
        if (tid < 48)  s_b[tid]  = ipb[l * 48 + tid];
        if (tid < 256) s_ow[tid] = outw[l * 256 + tid];
        if (tid < 16)  s_ob[tid] = outb[l * 16 + tid];
        __syncthreads();

        // ---- qkv = x @ W^T + b ; q kept in regs (pre-scaled), k/v to LDS ----
        float q[16];
        if (act) {
            #pragma unroll
            for (int o = 0; o < 16; ++o) {
                float a = s_b[o];
                #pragma unroll
                for (int i = 0; i < 16; ++i) a = fmaf(x[i], s_w[o * 16 + i], a);
                q[o] = a * SCALE_LOG2E;
            }
            #pragma unroll
            for (int o = 0; o < 16; ++o) {
                float a = s_b[16 + o];
                #pragma unroll
                for (int i = 0; i < 16; ++i) a = fmaf(x[i], s_w[(16 + o) * 16 + i], a);
                s_k[tid][o] = a;
            }
            #pragma unroll
            for (int o = 0; o < 16; ++o) {
                float a = s_b[32 + o];
                #pragma unroll
                for (int i = 0; i < 16; ++i) a = fmaf(x[i], s_w[(32 + o) * 16 + i], a);
                s_v[tid][o] = a;
            }
        }
        __syncthreads();

        // ---- attention: per-thread query row, loop over keys; max-free softmax ----
        if (act) {
            float acc[16];
            #pragma unroll
            for (int i = 0; i < 16; ++i) acc[i] = 0.0f;
            float lsum[4] = {0.0f, 0.0f, 0.0f, 0.0f};

            #pragma unroll 2
            for (int j = 0; j < K_; ++j) {
                const float4* kr = (const float4*)s_k[j];
                const float4 k0 = kr[0], k1 = kr[1], k2 = kr[2], k3 = kr[3];
                float s0 = fmaf(q[0],  k0.x, fmaf(q[1],  k0.y, fmaf(q[2],  k0.z, q[3]  * k0.w)));
                float s1 = fmaf(q[4],  k1.x, fmaf(q[5],  k1.y, fmaf(q[6],  k1.z, q[7]  * k1.w)));
                float s2 = fmaf(q[8],  k2.x, fmaf(q[9],  k2.y, fmaf(q[10], k2.z, q[11] * k2.w)));
                float s3 = fmaf(q[12], k3.x, fmaf(q[13], k3.y, fmaf(q[14], k3.z, q[15] * k3.w)));
                const float p0 = exp2f(s0);
                const float p1 = exp2f(s1);
                const float p2 = exp2f(s2);
                const float p3 = exp2f(s3);
                const float4* vr = (const float4*)s_v[j];
                const float4 v0 = vr[0], v1 = vr[1], v2 = vr[2], v3 = vr[3];
                lsum[0] += p0; lsum[1] += p1; lsum[2] += p2; lsum[3] += p3;
                acc[0]  = fmaf(p0, v0.x, acc[0]);  acc[1]  = fmaf(p0, v0.y, acc[1]);
                acc[2]  = fmaf(p0, v0.z, acc[2]);  acc[3]  = fmaf(p0, v0.w, acc[3]);
                acc[4]  = fmaf(p1, v1.x, acc[4]);  acc[5]  = fmaf(p1, v1.y, acc[5]);
                acc[6]  = fmaf(p1, v1.z, acc[6]);  acc[7]  = fmaf(p1, v1.w, acc[7]);
                acc[8]  = fmaf(p2, v2.x, acc[8]);  acc[9]  = fmaf(p2, v2.y, acc[9]);
                acc[10] = fmaf(p2, v2.z, acc[10]); acc[11] = fmaf(p2, v2.w, acc[11]);
                acc[12] = fmaf(p3, v3.x, acc[12]); acc[13] = fmaf(p3, v3.y, acc[13]);
                acc[14] = fmaf(p3, v3.z, acc[14]); acc[15] = fmaf(p3, v3.w, acc[15]);
            }

            const float inv0 = 1.0f / lsum[0];
            const float inv1 = 1.0f / lsum[1];
            const float inv2 = 1.0f / lsum[2];
            const float inv3 = 1.0f / lsum[3];
            float o_[16];
            #pragma unroll
            for (int d = 0; d < 4; ++d) {
                o_[d]      = acc[d]      * inv0;
                o_[4 + d]  = acc[4 + d]  * inv1;
                o_[8 + d]  = acc[8 + d]  * inv2;
                o_[12 + d] = acc[12 + d] * inv3;
            }

            // out projection
            float y[16];
            #pragma unroll
            for (int o = 0; o < 16; ++o) {
                float a = s_ob[o];
                #pragma unroll
                for (int i = 0; i < 16; ++i) a = fmaf(o_[i], s_ow[o * 16 + i], a);
                y[o] = a;
            }

            // residual + shared LayerNorm
            float t[16];
            float mu = 0.0f;
            #pragma unroll
            for (int i = 0; i < 16; ++i) { t[i] = y[i] + x[i]; mu += t[i]; }
            mu *= (1.0f / 16.0f);
            float var = 0.0f;
            #pragma unroll
            for (int i = 0; i < 16; ++i) { const float d = t[i] - mu; var = fmaf(d, d, var); }
            var *= (1.0f / 16.0f);
            const float rs = 1.0f / sqrtf(var + 1e-5f);
            #pragma unroll
            for (int i = 0; i < 16; ++i) x[i] = (t[i] - mu) * rs * s_lng[i] + s_lnb[i];
        }
    }

    if (act) {
        float4* o4 = (float4*)(out + (size_t)row * 16);
        o4[0] = make_float4(x[0],  x[1],  x[2],  x[3]);
        o4[1] = make_float4(x[4],  x[5],  x[6],  x[7]);
        o4[2] = make_float4(x[8],  x[9],  x[10], x[11]);
        o4[3] = make_float4(x[12], x[13], x[14], x[15]);
    }
}

extern "C" void kernel_launch(void* const* d_in, const int* in_sizes, int n_in,
                              void* d_out, int out_size, void* d_ws, size_t ws_size,
                              hipStream_t stream) {
    const float* pv      = (const float*)d_in[0];
    const int*   ele_idx = (const int*)  d_in[1];
    const int*   azi_idx = (const int*)  d_in[2];
    const float* vp_w    = (const float*)d_in[3];
    const float* vp_b    = (const float*)d_in[4];
    const float* ele_emb = (const float*)d_in[5];
    const float* azi_emb = (const float*)d_in[6];
    const float* ipw     = (const float*)d_in[7];
    const float* ipb     = (const float*)d_in[8];
    const float* outw    = (const float*)d_in[9];
    const float* outb    = (const float*)d_in[10];
    const float* lng     = (const float*)d_in[11];
    const float* lnb     = (const float*)d_in[12];
    float* out = (float*)d_out;

    mlra_kernel<<<R_, 256, 0, stream>>>(pv, ele_idx, azi_idx, vp_w, vp_b,
                                        ele_emb, azi_emb, ipw, ipb,
                                        outw, outb, lng, lnb, out);
}

// Round 3
// 184.848 us; speedup vs baseline: 1.2732x; 1.2732x over previous
//
#include <hip/hip_runtime.h>
#include <hip/hip_bf16.h>

#define R_ 512
#define K_ 250
#define E_ 16
#define L_ 2
#define KHALF 125

// fold 1/sqrt(D)=0.5 and log2(e) into q so softmax prob = exp2(dot)
#define SCALE_LOG2E 0.72134752044448170f

__global__ __launch_bounds__(512, 4)
void mlra_kernel(const float* __restrict__ pv,       // [R*K,8]
                 const int*   __restrict__ ele_idx,  // [R*K]
                 const int*   __restrict__ azi_idx,  // [R*K]
                 const float* __restrict__ vp_w,     // [8,8]
                 const float* __restrict__ vp_b,     // [8]
                 const float* __restrict__ ele_emb,  // [37,4]
                 const float* __restrict__ azi_emb,  // [107,4]
                 const float* __restrict__ ipw,      // [2,48,16]
                 const float* __restrict__ ipb,      // [2,48]
                 const float* __restrict__ outw,     // [2,16,16]
                 const float* __restrict__ outb,     // [2,16]
                 const float* __restrict__ lng,      // [16]
                 const float* __restrict__ lnb,      // [16]
                 float* __restrict__ out)            // [R*K,16]
{
    __shared__ float s_k[K_][E_];       // 16000 B
    __shared__ float s_v[K_][E_];       // 16000 B
    __shared__ float s_w[48 * 16];      // current layer in_proj weight
    __shared__ float s_b[48];
    __shared__ float s_ow[16 * 16];
    __shared__ float s_ob[16];
    __shared__ float s_vpw[64];
    __shared__ float s_vpb[8];
    __shared__ float s_ele[37 * 4];
    __shared__ float s_azi[107 * 4];
    __shared__ float s_lng[16], s_lnb[16];

    const int r   = blockIdx.x;
    const int tid = threadIdx.x;

    // ---- stage small constant tables ----
    if (tid < 64)  s_vpw[tid] = vp_w[tid];
    if (tid < 8)   s_vpb[tid] = vp_b[tid];
    for (int i = tid; i < 37 * 4;  i += 512) s_ele[i] = ele_emb[i];
    for (int i = tid; i < 107 * 4; i += 512) s_azi[i] = azi_emb[i];
    if (tid < 16) { s_lng[tid] = lng[tid]; s_lnb[tid] = lnb[tid]; }
    __syncthreads();

    // thread pair (qrow, half): partner lanes tid and tid^1 share one query,
    // each handles 125 of the 250 keys, combined via __shfl_xor at the end.
    const int  qrow = tid >> 1;
    const int  half = tid & 1;
    const bool act  = qrow < K_;
    const int  row  = r * K_ + qrow;

    // ---- prologue: x = concat(pv @ vp_w^T + vp_b, ele_emb[ei], azi_emb[ai]) ----
    float x[16];
    if (act) {
        const float4 p0 = ((const float4*)(pv + (size_t)row * 8))[0];
        const float4 p1 = ((const float4*)(pv + (size_t)row * 8))[1];
        const float pvv[8] = {p0.x, p0.y, p0.z, p0.w, p1.x, p1.y, p1.z, p1.w};
        #pragma unroll
        for (int o = 0; o < 8; ++o) {
            float a = s_vpb[o];
            #pragma unroll
            for (int i = 0; i < 8; ++i) a = fmaf(pvv[i], s_vpw[o * 8 + i], a);
            x[o] = a;
        }
        const int ei = ele_idx[row];
        const int ai = azi_idx[row];
        #pragma unroll
        for (int d = 0; d < 4; ++d) x[8 + d]  = s_ele[ei * 4 + d];
        #pragma unroll
        for (int d = 0; d < 4; ++d) x[12 + d] = s_azi[ai * 4 + d];
    }

    for (int l = 0; l < L_; ++l) {
        __syncthreads();   // previous-layer LDS consumers done before overwrite
        // stage layer weights
        for (int i = tid; i < 768; i += 512) s_w[i] = ipw[l * 768 + i];
        if (tid < 48)  s_b[tid]  = ipb[l * 48 + tid];
        if (tid < 256) s_ow[tid] = outw[l * 256 + tid];
        if (tid < 16)  s_ob[tid] = outb[l * 16 + tid];
        __syncthreads();

        // ---- qkv = x @ W^T + b ; q in regs (pre-scaled); half0 -> K, half1 -> V ----
        float q[16];
        if (act) {
            #pragma unroll
            for (int o = 0; o < 16; ++o) {
                float a = s_b[o];
                #pragma unroll
                for (int i = 0; i < 16; ++i) a = fmaf(x[i], s_w[o * 16 + i], a);
                q[o] = a * SCALE_LOG2E;
            }
            const int base = half ? 32 : 16;           // half0 writes K, half1 writes V
            float* dst = half ? s_v[qrow] : s_k[qrow];
            #pragma unroll
            for (int o = 0; o < 16; ++o) {
                float a = s_b[base + o];
                #pragma unroll
                for (int i = 0; i < 16; ++i) a = fmaf(x[i], s_w[(base + o) * 16 + i], a);
                dst[o] = a;
            }
        }
        __syncthreads();

        // ---- attention: each thread does 125 keys of its query; max-free softmax ----
        if (act) {
            float acc[16];
            #pragma unroll
            for (int i = 0; i < 16; ++i) acc[i] = 0.0f;
            float lsum[4] = {0.0f, 0.0f, 0.0f, 0.0f};

            const int j0 = half * KHALF;
            #pragma unroll 2
            for (int jj = 0; jj < KHALF; ++jj) {
                const int j = j0 + jj;
                const float4* kr = (const float4*)s_k[j];
                const float4 k0 = kr[0], k1 = kr[1], k2 = kr[2], k3 = kr[3];
                float s0 = fmaf(q[0],  k0.x, fmaf(q[1],  k0.y, fmaf(q[2],  k0.z, q[3]  * k0.w)));
                float s1 = fmaf(q[4],  k1.x, fmaf(q[5],  k1.y, fmaf(q[6],  k1.z, q[7]  * k1.w)));
                float s2 = fmaf(q[8],  k2.x, fmaf(q[9],  k2.y, fmaf(q[10], k2.z, q[11] * k2.w)));
                float s3 = fmaf(q[12], k3.x, fmaf(q[13], k3.y, fmaf(q[14], k3.z, q[15] * k3.w)));
                const float p0 = __builtin_amdgcn_exp2f(s0);
                const float p1 = __builtin_amdgcn_exp2f(s1);
                const float p2 = __builtin_amdgcn_exp2f(s2);
                const float p3 = __builtin_amdgcn_exp2f(s3);
                const float4* vr = (const float4*)s_v[j];
                const float4 v0 = vr[0], v1 = vr[1], v2 = vr[2], v3 = vr[3];
                lsum[0] += p0; lsum[1] += p1; lsum[2] += p2; lsum[3] += p3;
                acc[0]  = fmaf(p0, v0.x, acc[0]);  acc[1]  = fmaf(p0, v0.y, acc[1]);
                acc[2]  = fmaf(p0, v0.z, acc[2]);  acc[3]  = fmaf(p0, v0.w, acc[3]);
                acc[4]  = fmaf(p1, v1.x, acc[4]);  acc[5]  = fmaf(p1, v1.y, acc[5]);
                acc[6]  = fmaf(p1, v1.z, acc[6]);  acc[7]  = fmaf(p1, v1.w, acc[7]);
                acc[8]  = fmaf(p2, v2.x, acc[8]);  acc[9]  = fmaf(p2, v2.y, acc[9]);
                acc[10] = fmaf(p2, v2.z, acc[10]); acc[11] = fmaf(p2, v2.w, acc[11]);
                acc[12] = fmaf(p3, v3.x, acc[12]); acc[13] = fmaf(p3, v3.y, acc[13]);
                acc[14] = fmaf(p3, v3.z, acc[14]); acc[15] = fmaf(p3, v3.w, acc[15]);
            }

            // combine the two key-halves (partner = adjacent lane)
            #pragma unroll
            for (int i = 0; i < 16; ++i) acc[i] += __shfl_xor(acc[i], 1);
            #pragma unroll
            for (int c = 0; c < 4; ++c) lsum[c] += __shfl_xor(lsum[c], 1);

            const float inv0 = 1.0f / lsum[0];
            const float inv1 = 1.0f / lsum[1];
            const float inv2 = 1.0f / lsum[2];
            const float inv3 = 1.0f / lsum[3];
            float o_[16];
            #pragma unroll
            for (int d = 0; d < 4; ++d) {
                o_[d]      = acc[d]      * inv0;
                o_[4 + d]  = acc[4 + d]  * inv1;
                o_[8 + d]  = acc[8 + d]  * inv2;
                o_[12 + d] = acc[12 + d] * inv3;
            }

            // out projection
            float y[16];
            #pragma unroll
            for (int o = 0; o < 16; ++o) {
                float a = s_ob[o];
                #pragma unroll
                for (int i = 0; i < 16; ++i) a = fmaf(o_[i], s_ow[o * 16 + i], a);
                y[o] = a;
            }

            // residual + shared LayerNorm (both partners compute, keeps x in regs)
            float t[16];
            float mu = 0.0f;
            #pragma unroll
            for (int i = 0; i < 16; ++i) { t[i] = y[i] + x[i]; mu += t[i]; }
            mu *= (1.0f / 16.0f);
            float var = 0.0f;
            #pragma unroll
            for (int i = 0; i < 16; ++i) { const float d = t[i] - mu; var = fmaf(d, d, var); }
            var *= (1.0f / 16.0f);
            const float rs = 1.0f / sqrtf(var + 1e-5f);
            #pragma unroll
            for (int i = 0; i < 16; ++i) x[i] = (t[i] - mu) * rs * s_lng[i] + s_lnb[i];
        }
    }

    if (act && half == 0) {
        float4* o4 = (float4*)(out + (size_t)row * 16);
        o4[0] = make_float4(x[0],  x[1],  x[2],  x[3]);
        o4[1] = make_float4(x[4],  x[5],  x[6],  x[7]);
        o4[2] = make_float4(x[8],  x[9],  x[10], x[11]);
        o4[3] = make_float4(x[12], x[13], x[14], x[15]);
    }
}

extern "C" void kernel_launch(void* const* d_in, const int* in_sizes, int n_in,
                              void* d_out, int out_size, void* d_ws, size_t ws_size,
                              hipStream_t stream) {
    const float* pv      = (const float*)d_in[0];
    const int*   ele_idx = (const int*)  d_in[1];
    const int*   azi_idx = (const int*)  d_in[2];
    const float* vp_w    = (const float*)d_in[3];
    const float* vp_b    = (const float*)d_in[4];
    const float* ele_emb = (const float*)d_in[5];
    const float* azi_emb = (const float*)d_in[6];
    const float* ipw     = (const float*)d_in[7];
    const float* ipb     = (const float*)d_in[8];
    const float* outw    = (const float*)d_in[9];
    const float* outb    = (const float*)d_in[10];
    const float* lng     = (const float*)d_in[11];
    const float* lnb     = (const float*)d_in[12];
    float* out = (float*)d_out;

    mlra_kernel<<<R_, 512, 0, stream>>>(pv, ele_idx, azi_idx, vp_w, vp_b,
                                        ele_emb, azi_emb, ipw, ipb,
                                        outw, outb, lng, lnb, out);
}